// Round 5
// baseline (237.954 us; speedup 1.0000x reference)
//
#include <hip/hip_runtime.h>

#define BT   16
#define FIN  16
#define FOUT 32

typedef float  f32x4 __attribute__((ext_vector_type(4)));

// ---------------- CSR build ----------------

__global__ __launch_bounds__(256) void hist_kernel(const int* __restrict__ rows,
                                                   int* __restrict__ counts, int E) {
    int e = blockIdx.x * blockDim.x + threadIdx.x;
    if (e < E) atomicAdd(&counts[rows[e]], 1);
}

// 3-level scan over N=65536 counts
__global__ __launch_bounds__(256) void scan1_kernel(const int* __restrict__ counts,
                                                    int* __restrict__ row_start,
                                                    int* __restrict__ bsum) {
    __shared__ int sh[256];
    int t = threadIdx.x;
    int i = blockIdx.x * 256 + t;
    int v = counts[i];
    sh[t] = v;
    __syncthreads();
    for (int off = 1; off < 256; off <<= 1) {
        int u = (t >= off) ? sh[t - off] : 0;
        __syncthreads();
        sh[t] += u;
        __syncthreads();
    }
    row_start[i] = sh[t] - v;
    if (t == 255) bsum[blockIdx.x] = sh[255];
}

__global__ __launch_bounds__(256) void scan2_kernel(int* __restrict__ bsum,
                                                    int* __restrict__ boff,
                                                    int* __restrict__ row_start, int N) {
    __shared__ int sh[256];
    int t = threadIdx.x;
    int v = bsum[t];
    sh[t] = v;
    __syncthreads();
    for (int off = 1; off < 256; off <<= 1) {
        int u = (t >= off) ? sh[t - off] : 0;
        __syncthreads();
        sh[t] += u;
        __syncthreads();
    }
    boff[t] = sh[t] - v;
    if (t == 255) row_start[N] = sh[255];
}

__global__ __launch_bounds__(256) void scan3_kernel(int* __restrict__ row_start,
                                                    const int* __restrict__ boff) {
    int i = blockIdx.x * 256 + threadIdx.x;
    row_start[i] += boff[i >> 8];
}

// ---------------- fused: scatter (blocks [0, eb)) + gate_x (blocks [eb, eb+gb)) ----------------

__global__ __launch_bounds__(256) void scatter_gate_kernel(
        const int* __restrict__ rows, const int* __restrict__ cols,
        const float* __restrict__ vals,
        const int* __restrict__ row_start, int* __restrict__ cursor,
        int2* __restrict__ edge_s, int E, int eb,
        const float* __restrict__ water,  // [BT, N, 16]
        const float* __restrict__ st,     // [BT, N, 8]
        const float* __restrict__ Wg1, const float* __restrict__ bg1,
        const float* __restrict__ Wg2, const float* __restrict__ bg2,
        const float* __restrict__ min_gate,
        float* __restrict__ x, int N) {
    if (blockIdx.x < (unsigned)eb) {
        int e = blockIdx.x * 256 + threadIdx.x;
        if (e >= E) return;
        int r = rows[e];
        int pos = row_start[r] + atomicAdd(&cursor[r], 1);
        edge_s[pos] = make_int2(cols[e], __float_as_int(vals[e]));
    } else {
        int t = (blockIdx.x - eb) * 256 + threadIdx.x;
        if (t >= N * BT) return;
        int bt = t & (BT - 1);
        int n  = t >> 4;

        const f32x4* sp = (const f32x4*)(st + ((size_t)bt * N + n) * 8);
        f32x4 s0 = __builtin_nontemporal_load(sp);
        f32x4 s1 = __builtin_nontemporal_load(sp + 1);
        float g1 = s0.x * Wg1[0] + s0.y * Wg1[1] + s0.z * Wg1[2] + bg1[0];
        float g2 = s0.w * Wg2[0] + s1.x * Wg2[1] + s1.y * Wg2[2] + s1.z * Wg2[3] + s1.w * Wg2[4] + bg2[0];
        g1 = 1.f / (1.f + __expf(-g1));
        g2 = 1.f / (1.f + __expf(-g2));
        float gate = fmaxf(g1 * g2, min_gate[0]);

        const f32x4* wp = (const f32x4*)(water + ((size_t)bt * N + n) * FIN);
        f32x4*       xp = (f32x4*)(x + ((size_t)n * BT + bt) * FIN);
#pragma unroll
        for (int k = 0; k < 4; ++k) {
            f32x4 w = __builtin_nontemporal_load(wp + k);
            xp[k] = w * gate;   // cached: spmm re-reads x 9x
        }
    }
}

// ---------------- fused SpMM + 16->32 matmul + LayerNorm ----------------
// One wave per node; lane l gathers float4 = x[c][l*4 .. l*4+3].

#define EDGE_FMA(i)                                                              \
    do {                                                                         \
        float v = __int_as_float(d##i.y);                                        \
        acc += v * g##i;                                                         \
    } while (0)

__global__ __launch_bounds__(256) void spmm_ln_kernel(
        const float* __restrict__ x,          // [N, 256]
        const int* __restrict__ row_start,    // [N+1]
        const int2* __restrict__ edge_s,      // [E] {col, val}
        const float* __restrict__ W,          // [16, 32]
        const float* __restrict__ bvec,
        const float* __restrict__ gamma,
        const float* __restrict__ beta,
        float* __restrict__ out, int N) {     // out: [BT, N, 32]
    __shared__ float Wsh[FIN][FOUT];
    __shared__ float psh[3][FOUT];

    int t = threadIdx.x;
    Wsh[t >> 5][t & 31]       = W[t];
    Wsh[(t >> 5) + 8][t & 31] = W[t + 256];
    if (t < 32)       psh[0][t]      = bvec[t];
    else if (t < 64)  psh[1][t - 32] = gamma[t - 32];
    else if (t < 96)  psh[2][t - 64] = beta[t - 64];
    __syncthreads();

    int wave = t >> 6;
    int l    = t & 63;
    int n    = blockIdx.x * 4 + wave;

    int e0 = row_start[n], e1 = row_start[n + 1];
    const f32x4* xv = (const f32x4*)x;

    f32x4 acc = {0.f, 0.f, 0.f, 0.f};
    int e = e0;
    for (; e + 8 <= e1; e += 8) {
        int2 d0 = edge_s[e],     d1 = edge_s[e + 1], d2 = edge_s[e + 2], d3 = edge_s[e + 3];
        int2 d4 = edge_s[e + 4], d5 = edge_s[e + 5], d6 = edge_s[e + 6], d7 = edge_s[e + 7];
        f32x4 g0 = xv[(size_t)d0.x * 64 + l];
        f32x4 g1 = xv[(size_t)d1.x * 64 + l];
        f32x4 g2 = xv[(size_t)d2.x * 64 + l];
        f32x4 g3 = xv[(size_t)d3.x * 64 + l];
        f32x4 g4 = xv[(size_t)d4.x * 64 + l];
        f32x4 g5 = xv[(size_t)d5.x * 64 + l];
        f32x4 g6 = xv[(size_t)d6.x * 64 + l];
        f32x4 g7 = xv[(size_t)d7.x * 64 + l];
        EDGE_FMA(0); EDGE_FMA(1); EDGE_FMA(2); EDGE_FMA(3);
        EDGE_FMA(4); EDGE_FMA(5); EDGE_FMA(6); EDGE_FMA(7);
    }
    for (; e + 4 <= e1; e += 4) {
        int2 d0 = edge_s[e], d1 = edge_s[e + 1], d2 = edge_s[e + 2], d3 = edge_s[e + 3];
        f32x4 g0 = xv[(size_t)d0.x * 64 + l];
        f32x4 g1 = xv[(size_t)d1.x * 64 + l];
        f32x4 g2 = xv[(size_t)d2.x * 64 + l];
        f32x4 g3 = xv[(size_t)d3.x * 64 + l];
        EDGE_FMA(0); EDGE_FMA(1); EDGE_FMA(2); EDGE_FMA(3);
    }
    for (; e < e1; ++e) {
        int2 d0 = edge_s[e];
        f32x4 g0 = xv[(size_t)d0.x * 64 + l];
        EDGE_FMA(0);
    }

    // matmul: lane (bt = l>>2, d = l&3) computes out channels j = d*8 .. d*8+7
    int d = l & 3;
    float o[8];
#pragma unroll
    for (int jj = 0; jj < 8; ++jj) o[jj] = psh[0][d * 8 + jj];
#pragma unroll
    for (int q = 0; q < 4; ++q) {
        float hq[4];
        hq[0] = __shfl(acc.x, q, 4);
        hq[1] = __shfl(acc.y, q, 4);
        hq[2] = __shfl(acc.z, q, 4);
        hq[3] = __shfl(acc.w, q, 4);
#pragma unroll
        for (int m = 0; m < 4; ++m) {
            float hk = hq[m];
#pragma unroll
            for (int jj = 0; jj < 8; ++jj)
                o[jj] += hk * Wsh[q * 4 + m][d * 8 + jj];
        }
    }

    // LayerNorm over 32 channels: 4 lanes x 8 values
    float s = 0.f, sq = 0.f;
#pragma unroll
    for (int jj = 0; jj < 8; ++jj) { s += o[jj]; sq += o[jj] * o[jj]; }
    s  += __shfl_xor(s,  1, 4);  sq += __shfl_xor(sq, 1, 4);
    s  += __shfl_xor(s,  2, 4);  sq += __shfl_xor(sq, 2, 4);
    float mu  = s * (1.f / 32.f);
    float var = sq * (1.f / 32.f) - mu * mu;
    float inv = rsqrtf(var + 1e-3f);

    f32x4 r0, r1;
#pragma unroll
    for (int jj = 0; jj < 8; ++jj) {
        float val = (o[jj] - mu) * inv * psh[1][d * 8 + jj] + psh[2][d * 8 + jj];
        if (jj < 4) r0[jj] = val;
        else        r1[jj - 4] = val;
    }
    int bt = l >> 2;
    f32x4* op = (f32x4*)(out + (size_t)bt * N * FOUT + (size_t)n * FOUT + d * 8);
    __builtin_nontemporal_store(r0, op);      // out never re-read: don't evict x
    __builtin_nontemporal_store(r1, op + 1);
}

// ---------------- launch ----------------

extern "C" void kernel_launch(void* const* d_in, const int* in_sizes, int n_in,
                              void* d_out, int out_size, void* d_ws, size_t ws_size,
                              hipStream_t stream) {
    const float* water    = (const float*)d_in[0];
    const float* st       = (const float*)d_in[1];
    const int*   adj_rows = (const int*)  d_in[2];
    const int*   adj_cols = (const int*)  d_in[3];
    const float* adj_vals = (const float*)d_in[4];
    const float* W_feat   = (const float*)d_in[5];
    const float* b_feat   = (const float*)d_in[6];
    const float* Wg1      = (const float*)d_in[7];
    const float* bg1      = (const float*)d_in[8];
    const float* Wg2      = (const float*)d_in[9];
    const float* bg2      = (const float*)d_in[10];
    const float* ln_gamma = (const float*)d_in[11];
    const float* ln_beta  = (const float*)d_in[12];
    const float* min_gate = (const float*)d_in[13];
    float* out = (float*)d_out;

    int N = in_sizes[0] / (BT * FIN);
    int E = in_sizes[2];

    char* ws = (char*)d_ws;
    size_t off = 0;
    auto alloc = [&](size_t bytes) -> void* {
        off = (off + 255) & ~(size_t)255;
        void* p = ws + off;
        off += bytes;
        return p;
    };
    int*   counts    = (int*)  alloc((size_t)N * sizeof(int));
    int*   cursor    = (int*)  alloc((size_t)N * sizeof(int));   // contiguous with counts
    int*   row_start = (int*)  alloc((size_t)(N + 1) * sizeof(int));
    int*   bsum      = (int*)  alloc(256 * sizeof(int));
    int*   boff      = (int*)  alloc(256 * sizeof(int));
    int2*  edge_s    = (int2*) alloc((size_t)E * sizeof(int2));
    float* x         = (float*)alloc((size_t)N * BT * FIN * sizeof(float));

    (void)hipMemsetAsync(counts, 0, (size_t)2 * N * sizeof(int), stream);

    int eb = (E + 255) / 256;
    int gb = (N * BT + 255) / 256;
    int nb = N / 256;
    hist_kernel<<<eb, 256, 0, stream>>>(adj_rows, counts, E);
    scan1_kernel<<<nb, 256, 0, stream>>>(counts, row_start, bsum);
    scan2_kernel<<<1, 256, 0, stream>>>(bsum, boff, row_start, N);
    scan3_kernel<<<nb, 256, 0, stream>>>(row_start, boff);
    scatter_gate_kernel<<<eb + gb, 256, 0, stream>>>(
        adj_rows, adj_cols, adj_vals, row_start, cursor, edge_s, E, eb,
        water, st, Wg1, bg1, Wg2, bg2, min_gate, x, N);
    spmm_ln_kernel<<<N / 4, 256, 0, stream>>>(
        x, row_start, edge_s, W_feat, b_feat, ln_gamma, ln_beta, out, N);
}

// Round 6
// 183.485 us; speedup vs baseline: 1.2969x; 1.2969x over previous
//
#include <hip/hip_runtime.h>

#define BT   16
#define FIN  16
#define FOUT 32

typedef float    f32x4 __attribute__((ext_vector_type(4)));
typedef _Float16 f16x4 __attribute__((ext_vector_type(4)));
typedef _Float16 f16x8 __attribute__((ext_vector_type(8)));

// ---------------- fused: hist (blocks [0,eb)) + gate_x->fp16 (blocks [eb,eb+gb)) ----------------
// hist is atomic/latency-bound, gate_x is BW-bound; independent -> overlap.

__global__ __launch_bounds__(256) void hist_gate_kernel(
        const int* __restrict__ rows, int* __restrict__ counts, int E, int eb,
        const float* __restrict__ water,  // [BT, N, 16]
        const float* __restrict__ st,     // [BT, N, 8]
        const float* __restrict__ Wg1, const float* __restrict__ bg1,
        const float* __restrict__ Wg2, const float* __restrict__ bg2,
        const float* __restrict__ min_gate,
        _Float16* __restrict__ x, int N) {
    if (blockIdx.x < (unsigned)eb) {
        int e = blockIdx.x * 256 + threadIdx.x;
        if (e < E) atomicAdd(&counts[rows[e]], 1);
    } else {
        int t = (blockIdx.x - eb) * 256 + threadIdx.x;
        if (t >= N * BT) return;
        int bt = t & (BT - 1);
        int n  = t >> 4;

        const f32x4* sp = (const f32x4*)(st + ((size_t)bt * N + n) * 8);
        f32x4 s0 = __builtin_nontemporal_load(sp);
        f32x4 s1 = __builtin_nontemporal_load(sp + 1);
        float g1 = s0.x * Wg1[0] + s0.y * Wg1[1] + s0.z * Wg1[2] + bg1[0];
        float g2 = s0.w * Wg2[0] + s1.x * Wg2[1] + s1.y * Wg2[2] + s1.z * Wg2[3] + s1.w * Wg2[4] + bg2[0];
        g1 = 1.f / (1.f + __expf(-g1));
        g2 = 1.f / (1.f + __expf(-g2));
        float gate = fmaxf(g1 * g2, min_gate[0]);

        const f32x4* wp = (const f32x4*)(water + ((size_t)bt * N + n) * FIN);
        f16x8 h0, h1;
#pragma unroll
        for (int k = 0; k < 4; ++k) {
            f32x4 w = __builtin_nontemporal_load(wp + k);
            w *= gate;
            f16x8& h = (k < 2) ? h0 : h1;
            int b = (k & 1) * 4;
            h[b + 0] = (_Float16)w.x; h[b + 1] = (_Float16)w.y;
            h[b + 2] = (_Float16)w.z; h[b + 3] = (_Float16)w.w;
        }
        f16x8* xp = (f16x8*)(x + ((size_t)n * BT + bt) * FIN);
        xp[0] = h0;   // cached: spmm re-reads x 9x; 32MB -> L3-resident
        xp[1] = h1;
    }
}

// ---------------- CSR scans ----------------

__global__ __launch_bounds__(256) void scan1_kernel(const int* __restrict__ counts,
                                                    int* __restrict__ row_start,
                                                    int* __restrict__ bsum) {
    __shared__ int sh[256];
    int t = threadIdx.x;
    int i = blockIdx.x * 256 + t;
    int v = counts[i];
    sh[t] = v;
    __syncthreads();
    for (int off = 1; off < 256; off <<= 1) {
        int u = (t >= off) ? sh[t - off] : 0;
        __syncthreads();
        sh[t] += u;
        __syncthreads();
    }
    row_start[i] = sh[t] - v;                 // block-local exclusive
    if (t == 255) bsum[blockIdx.x] = sh[255];
}

__global__ __launch_bounds__(256) void scan2_kernel(const int* __restrict__ bsum,
                                                    int* __restrict__ boff,
                                                    int* __restrict__ row_start, int N) {
    __shared__ int sh[256];
    int t = threadIdx.x;
    int v = bsum[t];
    sh[t] = v;
    __syncthreads();
    for (int off = 1; off < 256; off <<= 1) {
        int u = (t >= off) ? sh[t - off] : 0;
        __syncthreads();
        sh[t] += u;
        __syncthreads();
    }
    boff[t] = sh[t] - v;                      // exclusive block offsets
    if (t == 255) {
        row_start[N] = sh[255];               // grand total (final value)
        boff[256]    = 0;                     // so rs[N]+boff[N>>8] == total
    }
}

// ---------------- scatter (boff folded in; no scan3) ----------------

__global__ __launch_bounds__(256) void scatter_kernel(const int* __restrict__ rows,
                                                      const int* __restrict__ cols,
                                                      const float* __restrict__ vals,
                                                      const int* __restrict__ row_start,
                                                      const int* __restrict__ boff,
                                                      int* __restrict__ cursor,
                                                      int2* __restrict__ edge_s, int E) {
    int e = blockIdx.x * blockDim.x + threadIdx.x;
    if (e >= E) return;
    int r = rows[e];
    int pos = row_start[r] + boff[r >> 8] + atomicAdd(&cursor[r], 1);
    edge_s[pos] = make_int2(cols[e], __float_as_int(vals[e]));
}

// ---------------- fused SpMM (fp16 x) + 16->32 matmul + LayerNorm ----------------
// One wave per node; lane l gathers f16x4 = x[c][l*4 .. l*4+3] (8B, 512B/wave).

#define EDGE_FMA(i)                                                              \
    do {                                                                         \
        float v = __int_as_float(d##i.y);                                        \
        acc.x += v * (float)g##i[0];                                             \
        acc.y += v * (float)g##i[1];                                             \
        acc.z += v * (float)g##i[2];                                             \
        acc.w += v * (float)g##i[3];                                             \
    } while (0)

__global__ __launch_bounds__(256) void spmm_ln_kernel(
        const _Float16* __restrict__ x,       // [N, 256] fp16
        const int* __restrict__ row_start,    // [N+1] block-local
        const int* __restrict__ boff,         // [257]
        const int2* __restrict__ edge_s,      // [E] {col, val}
        const float* __restrict__ W,          // [16, 32]
        const float* __restrict__ bvec,
        const float* __restrict__ gamma,
        const float* __restrict__ beta,
        float* __restrict__ out, int N) {     // out: [BT, N, 32]
    __shared__ float Wsh[FIN][FOUT];
    __shared__ float psh[3][FOUT];

    int t = threadIdx.x;
    Wsh[t >> 5][t & 31]       = W[t];
    Wsh[(t >> 5) + 8][t & 31] = W[t + 256];
    if (t < 32)       psh[0][t]      = bvec[t];
    else if (t < 64)  psh[1][t - 32] = gamma[t - 32];
    else if (t < 96)  psh[2][t - 64] = beta[t - 64];
    __syncthreads();

    int wave = t >> 6;
    int l    = t & 63;
    int n    = blockIdx.x * 4 + wave;

    int e0 = row_start[n]     + boff[n >> 8];
    int e1 = row_start[n + 1] + boff[(n + 1) >> 8];
    const f16x4* xv = (const f16x4*)x;        // node c -> xv[c*64 + l]

    f32x4 acc = {0.f, 0.f, 0.f, 0.f};
    int e = e0;
    for (; e + 8 <= e1; e += 8) {
        int2 d0 = edge_s[e],     d1 = edge_s[e + 1], d2 = edge_s[e + 2], d3 = edge_s[e + 3];
        int2 d4 = edge_s[e + 4], d5 = edge_s[e + 5], d6 = edge_s[e + 6], d7 = edge_s[e + 7];
        f16x4 g0 = xv[(size_t)d0.x * 64 + l];
        f16x4 g1 = xv[(size_t)d1.x * 64 + l];
        f16x4 g2 = xv[(size_t)d2.x * 64 + l];
        f16x4 g3 = xv[(size_t)d3.x * 64 + l];
        f16x4 g4 = xv[(size_t)d4.x * 64 + l];
        f16x4 g5 = xv[(size_t)d5.x * 64 + l];
        f16x4 g6 = xv[(size_t)d6.x * 64 + l];
        f16x4 g7 = xv[(size_t)d7.x * 64 + l];
        EDGE_FMA(0); EDGE_FMA(1); EDGE_FMA(2); EDGE_FMA(3);
        EDGE_FMA(4); EDGE_FMA(5); EDGE_FMA(6); EDGE_FMA(7);
    }
    for (; e + 4 <= e1; e += 4) {
        int2 d0 = edge_s[e], d1 = edge_s[e + 1], d2 = edge_s[e + 2], d3 = edge_s[e + 3];
        f16x4 g0 = xv[(size_t)d0.x * 64 + l];
        f16x4 g1 = xv[(size_t)d1.x * 64 + l];
        f16x4 g2 = xv[(size_t)d2.x * 64 + l];
        f16x4 g3 = xv[(size_t)d3.x * 64 + l];
        EDGE_FMA(0); EDGE_FMA(1); EDGE_FMA(2); EDGE_FMA(3);
    }
    for (; e < e1; ++e) {
        int2 d0 = edge_s[e];
        f16x4 g0 = xv[(size_t)d0.x * 64 + l];
        EDGE_FMA(0);
    }

    // matmul: lane (bt = l>>2, d = l&3) computes out channels j = d*8 .. d*8+7
    int d = l & 3;
    float o[8];
#pragma unroll
    for (int jj = 0; jj < 8; ++jj) o[jj] = psh[0][d * 8 + jj];
#pragma unroll
    for (int q = 0; q < 4; ++q) {
        float hq[4];
        hq[0] = __shfl(acc.x, q, 4);
        hq[1] = __shfl(acc.y, q, 4);
        hq[2] = __shfl(acc.z, q, 4);
        hq[3] = __shfl(acc.w, q, 4);
#pragma unroll
        for (int m = 0; m < 4; ++m) {
            float hk = hq[m];
#pragma unroll
            for (int jj = 0; jj < 8; ++jj)
                o[jj] += hk * Wsh[q * 4 + m][d * 8 + jj];
        }
    }

    // LayerNorm over 32 channels: 4 lanes x 8 values
    float s = 0.f, sq = 0.f;
#pragma unroll
    for (int jj = 0; jj < 8; ++jj) { s += o[jj]; sq += o[jj] * o[jj]; }
    s  += __shfl_xor(s,  1, 4);  sq += __shfl_xor(sq, 1, 4);
    s  += __shfl_xor(s,  2, 4);  sq += __shfl_xor(sq, 2, 4);
    float mu  = s * (1.f / 32.f);
    float var = sq * (1.f / 32.f) - mu * mu;
    float inv = rsqrtf(var + 1e-3f);

    f32x4 r0, r1;
#pragma unroll
    for (int jj = 0; jj < 8; ++jj) {
        float val = (o[jj] - mu) * inv * psh[1][d * 8 + jj] + psh[2][d * 8 + jj];
        if (jj < 4) r0[jj] = val;
        else        r1[jj - 4] = val;
    }
    int bt = l >> 2;
    f32x4* op = (f32x4*)(out + (size_t)bt * N * FOUT + (size_t)n * FOUT + d * 8);
    op[0] = r0;   // plain stores: L2 coalesces lines (nt store regressed in R5)
    op[1] = r1;
}

// ---------------- launch ----------------

extern "C" void kernel_launch(void* const* d_in, const int* in_sizes, int n_in,
                              void* d_out, int out_size, void* d_ws, size_t ws_size,
                              hipStream_t stream) {
    const float* water    = (const float*)d_in[0];
    const float* st       = (const float*)d_in[1];
    const int*   adj_rows = (const int*)  d_in[2];
    const int*   adj_cols = (const int*)  d_in[3];
    const float* adj_vals = (const float*)d_in[4];
    const float* W_feat   = (const float*)d_in[5];
    const float* b_feat   = (const float*)d_in[6];
    const float* Wg1      = (const float*)d_in[7];
    const float* bg1      = (const float*)d_in[8];
    const float* Wg2      = (const float*)d_in[9];
    const float* bg2      = (const float*)d_in[10];
    const float* ln_gamma = (const float*)d_in[11];
    const float* ln_beta  = (const float*)d_in[12];
    const float* min_gate = (const float*)d_in[13];
    float* out = (float*)d_out;

    int N = in_sizes[0] / (BT * FIN);
    int E = in_sizes[2];

    char* ws = (char*)d_ws;
    size_t off = 0;
    auto alloc = [&](size_t bytes) -> void* {
        off = (off + 255) & ~(size_t)255;
        void* p = ws + off;
        off += bytes;
        return p;
    };
    int*      counts    = (int*)     alloc((size_t)N * sizeof(int));
    int*      cursor    = (int*)     alloc((size_t)N * sizeof(int));   // contiguous with counts
    int*      row_start = (int*)     alloc((size_t)(N + 1) * sizeof(int));
    int*      bsum      = (int*)     alloc(256 * sizeof(int));
    int*      boff      = (int*)     alloc(257 * sizeof(int));
    int2*     edge_s    = (int2*)    alloc((size_t)E * sizeof(int2));
    _Float16* x         = (_Float16*)alloc((size_t)N * BT * FIN * sizeof(_Float16));

    (void)hipMemsetAsync(counts, 0, (size_t)2 * N * sizeof(int), stream);

    int eb = (E + 255) / 256;
    int gb = (N * BT + 255) / 256;
    int nb = N / 256;
    hist_gate_kernel<<<eb + gb, 256, 0, stream>>>(
        adj_rows, counts, E, eb,
        water, st, Wg1, bg1, Wg2, bg2, min_gate, x, N);
    scan1_kernel<<<nb, 256, 0, stream>>>(counts, row_start, bsum);
    scan2_kernel<<<1, 256, 0, stream>>>(bsum, boff, row_start, N);
    scatter_kernel<<<eb, 256, 0, stream>>>(adj_rows, adj_cols, adj_vals,
                                           row_start, boff, cursor, edge_s, E);
    spmm_ln_kernel<<<N / 4, 256, 0, stream>>>(
        x, row_start, boff, edge_s, W_feat, b_feat, ln_gamma, ln_beta, out, N);
}

// Round 7
// 180.698 us; speedup vs baseline: 1.3169x; 1.0154x over previous
//
#include <hip/hip_runtime.h>

#define BT   16
#define FIN  16
#define FOUT 32

typedef float    f32x4 __attribute__((ext_vector_type(4)));
typedef _Float16 f16x4 __attribute__((ext_vector_type(4)));
typedef _Float16 f16x8 __attribute__((ext_vector_type(8)));

// ---------------- zero counts (replaces pathological rocclr fill: 78us -> ~2us) ----------------

__global__ __launch_bounds__(256) void zero_kernel(int4* __restrict__ p) {
    p[blockIdx.x * 256 + threadIdx.x] = make_int4(0, 0, 0, 0);
}

// ---------------- fused: hist (blocks [0,eb)) + gate_x->fp16 (blocks [eb,eb+gb)) ----------------

__global__ __launch_bounds__(256) void hist_gate_kernel(
        const int* __restrict__ rows, int* __restrict__ counts, int E, int eb,
        const float* __restrict__ water,  // [BT, N, 16]
        const float* __restrict__ st,     // [BT, N, 8]
        const float* __restrict__ Wg1, const float* __restrict__ bg1,
        const float* __restrict__ Wg2, const float* __restrict__ bg2,
        const float* __restrict__ min_gate,
        _Float16* __restrict__ x, int N) {
    if (blockIdx.x < (unsigned)eb) {
        int e = blockIdx.x * 256 + threadIdx.x;
        if (e < E) atomicAdd(&counts[rows[e]], 1);
    } else {
        int t = (blockIdx.x - eb) * 256 + threadIdx.x;
        if (t >= N * BT) return;
        int bt = t & (BT - 1);
        int n  = t >> 4;

        const f32x4* sp = (const f32x4*)(st + ((size_t)bt * N + n) * 8);
        f32x4 s0 = __builtin_nontemporal_load(sp);
        f32x4 s1 = __builtin_nontemporal_load(sp + 1);
        float g1 = s0.x * Wg1[0] + s0.y * Wg1[1] + s0.z * Wg1[2] + bg1[0];
        float g2 = s0.w * Wg2[0] + s1.x * Wg2[1] + s1.y * Wg2[2] + s1.z * Wg2[3] + s1.w * Wg2[4] + bg2[0];
        g1 = 1.f / (1.f + __expf(-g1));
        g2 = 1.f / (1.f + __expf(-g2));
        float gate = fmaxf(g1 * g2, min_gate[0]);

        const f32x4* wp = (const f32x4*)(water + ((size_t)bt * N + n) * FIN);
        f16x8 h0, h1;
#pragma unroll
        for (int k = 0; k < 4; ++k) {
            f32x4 w = __builtin_nontemporal_load(wp + k);
            w *= gate;
            f16x8& h = (k < 2) ? h0 : h1;
            int b = (k & 1) * 4;
            h[b + 0] = (_Float16)w.x; h[b + 1] = (_Float16)w.y;
            h[b + 2] = (_Float16)w.z; h[b + 3] = (_Float16)w.w;
        }
        f16x8* xp = (f16x8*)(x + ((size_t)n * BT + bt) * FIN);
        xp[0] = h0;   // cached: spmm re-reads x 9x; 32MB -> L3-resident
        xp[1] = h1;
    }
}

// ---------------- CSR scans ----------------

__global__ __launch_bounds__(256) void scan1_kernel(const int* __restrict__ counts,
                                                    int* __restrict__ row_start,
                                                    int* __restrict__ bsum) {
    __shared__ int sh[256];
    int t = threadIdx.x;
    int i = blockIdx.x * 256 + t;
    int v = counts[i];
    sh[t] = v;
    __syncthreads();
    for (int off = 1; off < 256; off <<= 1) {
        int u = (t >= off) ? sh[t - off] : 0;
        __syncthreads();
        sh[t] += u;
        __syncthreads();
    }
    row_start[i] = sh[t] - v;                 // block-local exclusive
    if (t == 255) bsum[blockIdx.x] = sh[255];
}

__global__ __launch_bounds__(256) void scan2_kernel(const int* __restrict__ bsum,
                                                    int* __restrict__ boff,
                                                    int* __restrict__ row_start, int N) {
    __shared__ int sh[256];
    int t = threadIdx.x;
    int v = bsum[t];
    sh[t] = v;
    __syncthreads();
    for (int off = 1; off < 256; off <<= 1) {
        int u = (t >= off) ? sh[t - off] : 0;
        __syncthreads();
        sh[t] += u;
        __syncthreads();
    }
    boff[t] = sh[t] - v;                      // exclusive block offsets
    if (t == 255) row_start[N] = sh[255];     // grand total (already global)
}

// add-back to global offsets in-place AND init scatter cursors (no memset needed)
__global__ __launch_bounds__(256) void finalize_kernel(int* __restrict__ row_start,
                                                       const int* __restrict__ boff,
                                                       int* __restrict__ cur) {
    int i = blockIdx.x * 256 + threadIdx.x;
    int v = row_start[i] + boff[i >> 8];
    row_start[i] = v;
    cur[i] = v;
}

// ---------------- scatter ----------------

__global__ __launch_bounds__(256) void scatter_kernel(const int* __restrict__ rows,
                                                      const int* __restrict__ cols,
                                                      const float* __restrict__ vals,
                                                      int* __restrict__ cur,
                                                      int2* __restrict__ edge_s, int E) {
    int e = blockIdx.x * blockDim.x + threadIdx.x;
    if (e >= E) return;
    int pos = atomicAdd(&cur[rows[e]], 1);
    edge_s[pos] = make_int2(cols[e], __float_as_int(vals[e]));
}

// ---------------- fused SpMM (fp16 x) + 16->32 matmul + LayerNorm ----------------
// One wave per node; lane l gathers f16x4 = x[c][l*4 .. l*4+3] (8B, 512B/wave).

#define EDGE_FMA(i)                                                              \
    do {                                                                         \
        float v = __int_as_float(d##i.y);                                        \
        acc.x += v * (float)g##i[0];                                             \
        acc.y += v * (float)g##i[1];                                             \
        acc.z += v * (float)g##i[2];                                             \
        acc.w += v * (float)g##i[3];                                             \
    } while (0)

__global__ __launch_bounds__(256) void spmm_ln_kernel(
        const _Float16* __restrict__ x,       // [N, 256] fp16
        const int* __restrict__ row_start,    // [N+1] global
        const int2* __restrict__ edge_s,      // [E] {col, val}
        const float* __restrict__ W,          // [16, 32]
        const float* __restrict__ bvec,
        const float* __restrict__ gamma,
        const float* __restrict__ beta,
        float* __restrict__ out, int N) {     // out: [BT, N, 32]
    __shared__ float Wsh[FIN][FOUT];
    __shared__ float psh[3][FOUT];

    int t = threadIdx.x;
    Wsh[t >> 5][t & 31]       = W[t];
    Wsh[(t >> 5) + 8][t & 31] = W[t + 256];
    if (t < 32)       psh[0][t]      = bvec[t];
    else if (t < 64)  psh[1][t - 32] = gamma[t - 32];
    else if (t < 96)  psh[2][t - 64] = beta[t - 64];
    __syncthreads();

    int wave = t >> 6;
    int l    = t & 63;
    int n    = blockIdx.x * 4 + wave;

    int e0 = row_start[n], e1 = row_start[n + 1];
    const f16x4* xv = (const f16x4*)x;        // node c -> xv[c*64 + l]

    f32x4 acc = {0.f, 0.f, 0.f, 0.f};
    int e = e0;
    for (; e + 8 <= e1; e += 8) {
        int2 d0 = edge_s[e],     d1 = edge_s[e + 1], d2 = edge_s[e + 2], d3 = edge_s[e + 3];
        int2 d4 = edge_s[e + 4], d5 = edge_s[e + 5], d6 = edge_s[e + 6], d7 = edge_s[e + 7];
        f16x4 g0 = xv[(size_t)d0.x * 64 + l];
        f16x4 g1 = xv[(size_t)d1.x * 64 + l];
        f16x4 g2 = xv[(size_t)d2.x * 64 + l];
        f16x4 g3 = xv[(size_t)d3.x * 64 + l];
        f16x4 g4 = xv[(size_t)d4.x * 64 + l];
        f16x4 g5 = xv[(size_t)d5.x * 64 + l];
        f16x4 g6 = xv[(size_t)d6.x * 64 + l];
        f16x4 g7 = xv[(size_t)d7.x * 64 + l];
        EDGE_FMA(0); EDGE_FMA(1); EDGE_FMA(2); EDGE_FMA(3);
        EDGE_FMA(4); EDGE_FMA(5); EDGE_FMA(6); EDGE_FMA(7);
    }
    for (; e + 4 <= e1; e += 4) {
        int2 d0 = edge_s[e], d1 = edge_s[e + 1], d2 = edge_s[e + 2], d3 = edge_s[e + 3];
        f16x4 g0 = xv[(size_t)d0.x * 64 + l];
        f16x4 g1 = xv[(size_t)d1.x * 64 + l];
        f16x4 g2 = xv[(size_t)d2.x * 64 + l];
        f16x4 g3 = xv[(size_t)d3.x * 64 + l];
        EDGE_FMA(0); EDGE_FMA(1); EDGE_FMA(2); EDGE_FMA(3);
    }
    for (; e < e1; ++e) {
        int2 d0 = edge_s[e];
        f16x4 g0 = xv[(size_t)d0.x * 64 + l];
        EDGE_FMA(0);
    }

    // matmul: lane (bt = l>>2, d = l&3) computes out channels j = d*8 .. d*8+7
    int d = l & 3;
    float o[8];
#pragma unroll
    for (int jj = 0; jj < 8; ++jj) o[jj] = psh[0][d * 8 + jj];
#pragma unroll
    for (int q = 0; q < 4; ++q) {
        float hq[4];
        hq[0] = __shfl(acc.x, q, 4);
        hq[1] = __shfl(acc.y, q, 4);
        hq[2] = __shfl(acc.z, q, 4);
        hq[3] = __shfl(acc.w, q, 4);
#pragma unroll
        for (int m = 0; m < 4; ++m) {
            float hk = hq[m];
#pragma unroll
            for (int jj = 0; jj < 8; ++jj)
                o[jj] += hk * Wsh[q * 4 + m][d * 8 + jj];
        }
    }

    // LayerNorm over 32 channels: 4 lanes x 8 values
    float s = 0.f, sq = 0.f;
#pragma unroll
    for (int jj = 0; jj < 8; ++jj) { s += o[jj]; sq += o[jj] * o[jj]; }
    s  += __shfl_xor(s,  1, 4);  sq += __shfl_xor(sq, 1, 4);
    s  += __shfl_xor(s,  2, 4);  sq += __shfl_xor(sq, 2, 4);
    float mu  = s * (1.f / 32.f);
    float var = sq * (1.f / 32.f) - mu * mu;
    float inv = rsqrtf(var + 1e-3f);

    f32x4 r0, r1;
#pragma unroll
    for (int jj = 0; jj < 8; ++jj) {
        float val = (o[jj] - mu) * inv * psh[1][d * 8 + jj] + psh[2][d * 8 + jj];
        if (jj < 4) r0[jj] = val;
        else        r1[jj - 4] = val;
    }
    int bt = l >> 2;
    f32x4* op = (f32x4*)(out + (size_t)bt * N * FOUT + (size_t)n * FOUT + d * 8);
    op[0] = r0;   // plain stores: L2 coalesces lines (nt store regressed in R5)
    op[1] = r1;
}

// ---------------- launch ----------------

extern "C" void kernel_launch(void* const* d_in, const int* in_sizes, int n_in,
                              void* d_out, int out_size, void* d_ws, size_t ws_size,
                              hipStream_t stream) {
    const float* water    = (const float*)d_in[0];
    const float* st       = (const float*)d_in[1];
    const int*   adj_rows = (const int*)  d_in[2];
    const int*   adj_cols = (const int*)  d_in[3];
    const float* adj_vals = (const float*)d_in[4];
    const float* W_feat   = (const float*)d_in[5];
    const float* b_feat   = (const float*)d_in[6];
    const float* Wg1      = (const float*)d_in[7];
    const float* bg1      = (const float*)d_in[8];
    const float* Wg2      = (const float*)d_in[9];
    const float* bg2      = (const float*)d_in[10];
    const float* ln_gamma = (const float*)d_in[11];
    const float* ln_beta  = (const float*)d_in[12];
    const float* min_gate = (const float*)d_in[13];
    float* out = (float*)d_out;

    int N = in_sizes[0] / (BT * FIN);
    int E = in_sizes[2];

    char* ws = (char*)d_ws;
    size_t off = 0;
    auto alloc = [&](size_t bytes) -> void* {
        off = (off + 255) & ~(size_t)255;
        void* p = ws + off;
        off += bytes;
        return p;
    };
    int*      counts    = (int*)     alloc((size_t)N * sizeof(int));
    int*      cur       = (int*)     alloc((size_t)N * sizeof(int));
    int*      row_start = (int*)     alloc((size_t)(N + 1) * sizeof(int));
    int*      bsum      = (int*)     alloc(256 * sizeof(int));
    int*      boff      = (int*)     alloc(256 * sizeof(int));
    int2*     edge_s    = (int2*)    alloc((size_t)E * sizeof(int2));
    _Float16* x         = (_Float16*)alloc((size_t)N * BT * FIN * sizeof(_Float16));

    int eb = (E + 255) / 256;
    int gb = (N * BT + 255) / 256;
    int nb = N / 256;                          // 256 blocks for N=65536

    zero_kernel<<<N / 1024, 256, 0, stream>>>((int4*)counts);   // counts only; cur set by finalize
    hist_gate_kernel<<<eb + gb, 256, 0, stream>>>(
        adj_rows, counts, E, eb,
        water, st, Wg1, bg1, Wg2, bg2, min_gate, x, N);
    scan1_kernel<<<nb, 256, 0, stream>>>(counts, row_start, bsum);
    scan2_kernel<<<1, 256, 0, stream>>>(bsum, boff, row_start, N);
    finalize_kernel<<<nb, 256, 0, stream>>>(row_start, boff, cur);
    scatter_kernel<<<eb, 256, 0, stream>>>(adj_rows, adj_cols, adj_vals,
                                           cur, edge_s, E);
    spmm_ln_kernel<<<N / 4, 256, 0, stream>>>(
        x, row_start, edge_s, W_feat, b_feat, ln_gamma, ln_beta, out, N);
}